// Round 1
// baseline (294.854 us; speedup 1.0000x reference)
//
#include <hip/hip_runtime.h>
#include <hip/hip_bf16.h>
#include <math.h>

// Problem constants (from reference module)
#define LENGTH_MIN 5
#define LENGTH_MAX 64
#define EMBED_DIM 512
#define HDIM      256
#define POOL      20
#define TOPK      5
#define BETA      0.5f
#define LN_EPS    1e-5f
#define COS_EPS   1e-8f

// ws layout (floats):
//   [0]      qmean
//   [1..5]   mw1, mb1, Vw1, Vb1, Cov(w1,b1)
//   [8..27]  inv key norms
//   [32 ..]            topw  [B][5] float
//   [32+5B ..]         topidx[B][5] int
//   [32+10B ..]        len   [B]    int

__device__ __forceinline__ float blockReduceSum(float v, float* red) {
    int t = threadIdx.x;
    red[t] = v;
    __syncthreads();
    for (int off = 128; off > 0; off >>= 1) {
        if (t < off) red[t] += red[t + off];
        __syncthreads();
    }
    float r = red[0];
    __syncthreads();
    return r;
}

// Block 0: quality mean. Block 1: w1/b1 stats. Blocks 2..21: key inverse norms.
__global__ __launch_bounds__(256) void prep_kernel(
    const float* __restrict__ quality, const float* __restrict__ keys,
    const float* __restrict__ w1, const float* __restrict__ b1,
    float* __restrict__ ws, int B)
{
    __shared__ float red[256];
    int t = threadIdx.x;
    int blk = blockIdx.x;
    if (blk == 0) {
        float s = 0.f;
        for (int i = t; i < B; i += 256) s += quality[i];
        float tot = blockReduceSum(s, red);
        if (t == 0) ws[0] = tot / (float)B;
    } else if (blk == 1) {
        float a = w1[t];      // H == 256 == blockDim
        float c = b1[t];
        float mw1 = blockReduceSum(a, red) / 256.f;
        float mb1 = blockReduceSum(c, red) / 256.f;
        float da = a - mw1, dc = c - mb1;
        float Vw1 = blockReduceSum(da * da, red) / 256.f;
        float Vb1 = blockReduceSum(dc * dc, red) / 256.f;
        float Cv  = blockReduceSum(da * dc, red) / 256.f;
        if (t == 0) { ws[1] = mw1; ws[2] = mb1; ws[3] = Vw1; ws[4] = Vb1; ws[5] = Cv; }
    } else {
        int p = blk - 2;                     // 0..19
        const float* kp = keys + p * EMBED_DIM;
        float s = 0.f;
        float x0 = kp[t], x1 = kp[t + 256];
        s = x0 * x0 + x1 * x1;
        float n2 = blockReduceSum(s, red);
        if (t == 0) ws[8 + p] = 1.f / fmaxf(sqrtf(n2), COS_EPS);
    }
}

// 4 batches per block, 256 threads. Computes query = relu(LN(q*w1+b1))@w2+b2,
// cosine sims vs pool keys, softmax(scale), top-5, and dynamic length.
__global__ __launch_bounds__(256) void query_kernel(
    const float* __restrict__ quality, const float* __restrict__ keys,
    const float* __restrict__ w1, const float* __restrict__ b1,
    const float* __restrict__ ln_g, const float* __restrict__ ln_b,
    const float* __restrict__ w2, const float* __restrict__ b2,
    float* __restrict__ ws, int B)
{
    __shared__ float hn_s[4][HDIM];
    __shared__ float qbuf[4][EMBED_DIM];
    int t = threadIdx.x;
    int b0 = blockIdx.x * 4;

    float qmean = ws[0];
    float mw1 = ws[1], mb1 = ws[2], Vw1 = ws[3], Vb1 = ws[4], Cv = ws[5];
    float invk[POOL];
    #pragma unroll
    for (int p = 0; p < POOL; p++) invk[p] = ws[8 + p];

    float w1t = w1[t], b1t = b1[t], gt = ln_g[t], lbt = ln_b[t];
    float qv4[4];
    #pragma unroll
    for (int bi = 0; bi < 4; bi++) {
        float q = quality[b0 + bi];
        qv4[bi] = q;
        float mu  = q * mw1 + mb1;
        float var = q * q * Vw1 + 2.f * q * Cv + Vb1;
        float inv = rsqrtf(var + LN_EPS);
        float h = q * w1t + b1t;
        float v = (h - mu) * inv * gt + lbt;
        hn_s[bi][t] = fmaxf(v, 0.f);
    }
    __syncthreads();

    // query: thread t -> columns d0, d0+1
    int d0 = 2 * t;
    float2 b2v = *(const float2*)(b2 + d0);
    float acc0[4], acc1[4];
    #pragma unroll
    for (int bi = 0; bi < 4; bi++) { acc0[bi] = b2v.x; acc1[bi] = b2v.y; }

    for (int j = 0; j < HDIM; j += 4) {
        float2 wv0 = *(const float2*)(w2 + (j + 0) * EMBED_DIM + d0);
        float2 wv1 = *(const float2*)(w2 + (j + 1) * EMBED_DIM + d0);
        float2 wv2 = *(const float2*)(w2 + (j + 2) * EMBED_DIM + d0);
        float2 wv3 = *(const float2*)(w2 + (j + 3) * EMBED_DIM + d0);
        #pragma unroll
        for (int bi = 0; bi < 4; bi++) {
            float4 hv = *(const float4*)&hn_s[bi][j];
            acc0[bi] = fmaf(hv.x, wv0.x, acc0[bi]);
            acc1[bi] = fmaf(hv.x, wv0.y, acc1[bi]);
            acc0[bi] = fmaf(hv.y, wv1.x, acc0[bi]);
            acc1[bi] = fmaf(hv.y, wv1.y, acc1[bi]);
            acc0[bi] = fmaf(hv.z, wv2.x, acc0[bi]);
            acc1[bi] = fmaf(hv.z, wv2.y, acc1[bi]);
            acc0[bi] = fmaf(hv.w, wv3.x, acc0[bi]);
            acc1[bi] = fmaf(hv.w, wv3.y, acc1[bi]);
        }
    }
    #pragma unroll
    for (int bi = 0; bi < 4; bi++) {
        *(float2*)&qbuf[bi][d0] = make_float2(acc0[bi], acc1[bi]);
    }
    __syncthreads();

    // one wave per batch: norm, sims, softmax, top-5
    int wave = t >> 6, lane = t & 63;
    int bi = wave;
    float s[POOL + 1];
    #pragma unroll
    for (int p = 0; p <= POOL; p++) s[p] = 0.f;
    #pragma unroll
    for (int i = 0; i < 8; i++) {
        int d = lane + 64 * i;
        float qd = qbuf[bi][d];
        s[POOL] = fmaf(qd, qd, s[POOL]);
        #pragma unroll
        for (int p = 0; p < POOL; p++)
            s[p] = fmaf(qd, keys[p * EMBED_DIM + d], s[p]);
    }
    #pragma unroll
    for (int off = 32; off > 0; off >>= 1) {
        #pragma unroll
        for (int p = 0; p <= POOL; p++) s[p] += __shfl_xor(s[p], off);
    }

    float invq = 1.f / fmaxf(sqrtf(s[POOL]), COS_EPS);
    float scale = 1.f + BETA * qmean;
    float sim[POOL];
    #pragma unroll
    for (int p = 0; p < POOL; p++) sim[p] = s[p] * invq * invk[p] * scale;

    float m = sim[0];
    #pragma unroll
    for (int p = 1; p < POOL; p++) m = fmaxf(m, sim[p]);
    float e[POOL]; float den = 0.f;
    #pragma unroll
    for (int p = 0; p < POOL; p++) { e[p] = __expf(sim[p] - m); den += e[p]; }
    // use precise expf for safety
    den = 0.f;
    #pragma unroll
    for (int p = 0; p < POOL; p++) { e[p] = expf(sim[p] - m); den += e[p]; }
    float invden = 1.f / den;

    unsigned picked = 0;
    float tw[TOPK]; int ti[TOPK];
    #pragma unroll
    for (int k = 0; k < TOPK; k++) {
        float best = -1.f; int bidx = 0;
        #pragma unroll
        for (int p = 0; p < POOL; p++) {
            bool free_p = ((picked >> p) & 1u) == 0u;
            if (free_p && e[p] > best) { best = e[p]; bidx = p; }
        }
        picked |= (1u << bidx);
        tw[k] = best * invden;
        ti[k] = bidx;
    }

    if (lane == 0) {
        int b = b0 + bi;
        float* topw = ws + 32;
        int*   topi = (int*)(ws + 32) + 5 * B;
        int*   lenp = (int*)(ws + 32) + 10 * B;
        #pragma unroll
        for (int k = 0; k < TOPK; k++) {
            topw[b * TOPK + k] = tw[k];
            topi[b * TOPK + k] = ti[k];
        }
        float q = qv4[bi];
        float lf = __fadd_rn(5.f, __fmul_rn(59.f, __fsub_rn(1.f, __fdiv_rn(q, 5.f))));
        int len = (int)truncf(lf);
        len = min(max(len, LENGTH_MIN), LENGTH_MAX);
        lenp[b] = len;
    }
}

// out[b,l,:] = (l < len[b]) ? sum_k w_k * pe[idx_k, l, :] : 0
// One block handles (b, 8 consecutive l rows). float4 everywhere.
__global__ __launch_bounds__(256) void scatter_kernel(
    const float* __restrict__ pe, const float* __restrict__ ws,
    float* __restrict__ out, int B)
{
    int b  = blockIdx.x >> 3;
    int l0 = (blockIdx.x & 7) * 8;
    const float* topw = ws + 32;
    const int*   topi = (const int*)(ws + 32) + 5 * B;
    const int*   lenp = (const int*)(ws + 32) + 10 * B;

    float w[TOPK]; int idx[TOPK];
    #pragma unroll
    for (int k = 0; k < TOPK; k++) {
        w[k]   = topw[b * TOPK + k];
        idx[k] = topi[b * TOPK + k];
    }
    int len = lenp[b];

    int t = threadIdx.x;
    #pragma unroll
    for (int sweep = 0; sweep < 4; sweep++) {
        int l  = l0 + sweep * 2 + (t >> 7);
        int d4 = (t & 127) * 4;
        float4 r = make_float4(0.f, 0.f, 0.f, 0.f);
        if (l < len) {
            #pragma unroll
            for (int k = 0; k < TOPK; k++) {
                const float4 pv = *(const float4*)(pe + (idx[k] * 64 + l) * EMBED_DIM + d4);
                r.x = fmaf(w[k], pv.x, r.x);
                r.y = fmaf(w[k], pv.y, r.y);
                r.z = fmaf(w[k], pv.z, r.z);
                r.w = fmaf(w[k], pv.w, r.w);
            }
        }
        *(float4*)(out + ((size_t)(b * 64 + l)) * EMBED_DIM + d4) = r;
    }
}

extern "C" void kernel_launch(void* const* d_in, const int* in_sizes, int n_in,
                              void* d_out, int out_size, void* d_ws, size_t ws_size,
                              hipStream_t stream) {
    // input order: x_embed(unused), quality, keys, prompt_embeddings, w1, b1, ln_g, ln_b, w2, b2
    const float* quality = (const float*)d_in[1];
    const float* keys    = (const float*)d_in[2];
    const float* pe      = (const float*)d_in[3];
    const float* w1      = (const float*)d_in[4];
    const float* b1      = (const float*)d_in[5];
    const float* ln_g    = (const float*)d_in[6];
    const float* ln_b    = (const float*)d_in[7];
    const float* w2      = (const float*)d_in[8];
    const float* b2      = (const float*)d_in[9];
    float* out = (float*)d_out;
    float* ws  = (float*)d_ws;
    int B = in_sizes[1];

    prep_kernel<<<2 + POOL, 256, 0, stream>>>(quality, keys, w1, b1, ws, B);
    query_kernel<<<B / 4, 256, 0, stream>>>(quality, keys, w1, b1, ln_g, ln_b, w2, b2, ws, B);
    scatter_kernel<<<B * 8, 256, 0, stream>>>(pe, ws, out, B);
}

// Round 2
// 274.201 us; speedup vs baseline: 1.0753x; 1.0753x over previous
//
#include <hip/hip_runtime.h>
#include <hip/hip_bf16.h>
#include <math.h>

// Problem constants (from reference module)
#define LENGTH_MIN 5
#define LENGTH_MAX 64
#define EMBED_DIM 512
#define HDIM      256
#define POOL      20
#define TOPK      5
#define BETA      0.5f
#define LN_EPS    1e-5f
#define COS_EPS   1e-8f

typedef float v4f __attribute__((ext_vector_type(4)));

// ws layout (floats):
//   [32 ..]            topw  [B][5] float
//   [32+5B ..]         topidx[B][5] int
//   [32+10B ..]        len   [B]    int

// Fused kernel: per-block redundant prep (quality mean, w1/b1 LN stats in
// closed form, key inverse norms) + query projection + cosine sims + softmax
// + top-5 + dynamic length. 4 batches per block, 256 threads.
// Redundant prep is cheap: quality (4 KB), w1/b1 (1 KB), keys (40 KB) are
// L2-resident broadcast reads.
__global__ __launch_bounds__(256) void query_all_kernel(
    const float* __restrict__ quality, const float* __restrict__ keys,
    const float* __restrict__ w1, const float* __restrict__ b1,
    const float* __restrict__ ln_g, const float* __restrict__ ln_b,
    const float* __restrict__ w2, const float* __restrict__ b2,
    float* __restrict__ ws, int B)
{
    __shared__ float red[24];          // 6 reduction values x 4 waves
    __shared__ float invk_s[POOL];
    __shared__ float hn_s[4][HDIM];
    __shared__ float qbuf[4][EMBED_DIM];

    int t = threadIdx.x;
    int wave = t >> 6, lane = t & 63;
    int b0 = blockIdx.x * 4;

    // ---- redundant prep: 6 block-reductions batched into ONE __syncthreads ----
    float qpart = 0.f;
    for (int i = t; i < B; i += 256) qpart += quality[i];
    float a = w1[t], c = b1[t];        // HDIM == 256 == blockDim
    float vals[6] = { qpart, a, a * a, c, c * c, a * c };
    #pragma unroll
    for (int i = 0; i < 6; i++) {
        float v = vals[i];
        #pragma unroll
        for (int off = 32; off > 0; off >>= 1) v += __shfl_xor(v, off);
        if (lane == 0) red[i * 4 + wave] = v;
    }
    // key inverse norms: wave w handles keys {w, w+4, ..., w+16}
    #pragma unroll
    for (int j = 0; j < 5; j++) {
        int p = wave + 4 * j;
        const float* kp = keys + p * EMBED_DIM;
        float s = 0.f;
        #pragma unroll
        for (int i = 0; i < 8; i++) { float x = kp[lane + 64 * i]; s = fmaf(x, x, s); }
        #pragma unroll
        for (int off = 32; off > 0; off >>= 1) s += __shfl_xor(s, off);
        if (lane == 0) invk_s[p] = 1.f / fmaxf(sqrtf(s), COS_EPS);
    }
    __syncthreads();

    float qmean = (red[0] + red[1] + red[2] + red[3]) / (float)B;
    float mw1   = (red[4] + red[5] + red[6] + red[7]) * (1.f / 256.f);
    float Ew2   = (red[8] + red[9] + red[10] + red[11]) * (1.f / 256.f);
    float mb1   = (red[12] + red[13] + red[14] + red[15]) * (1.f / 256.f);
    float Eb2   = (red[16] + red[17] + red[18] + red[19]) * (1.f / 256.f);
    float Eab   = (red[20] + red[21] + red[22] + red[23]) * (1.f / 256.f);
    float Vw1 = Ew2 - mw1 * mw1;
    float Vb1 = Eb2 - mb1 * mb1;
    float Cv  = Eab - mw1 * mb1;

    // ---- LN(q*w1+b1) -> relu, closed-form stats (quadratic in scalar q) ----
    float gt = ln_g[t], lbt = ln_b[t];
    float qv4[4];
    #pragma unroll
    for (int bi = 0; bi < 4; bi++) {
        float q = quality[b0 + bi];
        qv4[bi] = q;
        float mu  = q * mw1 + mb1;
        float var = q * q * Vw1 + 2.f * q * Cv + Vb1;
        float inv = rsqrtf(var + LN_EPS);
        float h = q * a + c;
        hn_s[bi][t] = fmaxf((h - mu) * inv * gt + lbt, 0.f);
    }
    __syncthreads();

    // ---- query = hn @ w2 + b2 : thread t -> columns 2t, 2t+1, 4 batches ----
    int d0 = 2 * t;
    float2 b2v = *(const float2*)(b2 + d0);
    float acc0[4], acc1[4];
    #pragma unroll
    for (int bi = 0; bi < 4; bi++) { acc0[bi] = b2v.x; acc1[bi] = b2v.y; }

    for (int j = 0; j < HDIM; j += 4) {
        float2 wv0 = *(const float2*)(w2 + (j + 0) * EMBED_DIM + d0);
        float2 wv1 = *(const float2*)(w2 + (j + 1) * EMBED_DIM + d0);
        float2 wv2 = *(const float2*)(w2 + (j + 2) * EMBED_DIM + d0);
        float2 wv3 = *(const float2*)(w2 + (j + 3) * EMBED_DIM + d0);
        #pragma unroll
        for (int bi = 0; bi < 4; bi++) {
            float4 hv = *(const float4*)&hn_s[bi][j];
            acc0[bi] = fmaf(hv.x, wv0.x, acc0[bi]);
            acc1[bi] = fmaf(hv.x, wv0.y, acc1[bi]);
            acc0[bi] = fmaf(hv.y, wv1.x, acc0[bi]);
            acc1[bi] = fmaf(hv.y, wv1.y, acc1[bi]);
            acc0[bi] = fmaf(hv.z, wv2.x, acc0[bi]);
            acc1[bi] = fmaf(hv.z, wv2.y, acc1[bi]);
            acc0[bi] = fmaf(hv.w, wv3.x, acc0[bi]);
            acc1[bi] = fmaf(hv.w, wv3.y, acc1[bi]);
        }
    }
    #pragma unroll
    for (int bi = 0; bi < 4; bi++)
        *(float2*)&qbuf[bi][d0] = make_float2(acc0[bi], acc1[bi]);
    __syncthreads();

    // ---- one wave per batch: norm, sims, softmax, top-5, length ----
    int bi = wave;
    float s[POOL + 1];
    #pragma unroll
    for (int p = 0; p <= POOL; p++) s[p] = 0.f;
    #pragma unroll
    for (int i = 0; i < 8; i++) {
        int d = lane + 64 * i;
        float qd = qbuf[bi][d];
        s[POOL] = fmaf(qd, qd, s[POOL]);
        #pragma unroll
        for (int p = 0; p < POOL; p++)
            s[p] = fmaf(qd, keys[p * EMBED_DIM + d], s[p]);
    }
    #pragma unroll
    for (int off = 32; off > 0; off >>= 1) {
        #pragma unroll
        for (int p = 0; p <= POOL; p++) s[p] += __shfl_xor(s[p], off);
    }

    float invq  = 1.f / fmaxf(sqrtf(s[POOL]), COS_EPS);
    float scale = 1.f + BETA * qmean;
    float sim[POOL];
    #pragma unroll
    for (int p = 0; p < POOL; p++) sim[p] = s[p] * invq * invk_s[p] * scale;

    float m = sim[0];
    #pragma unroll
    for (int p = 1; p < POOL; p++) m = fmaxf(m, sim[p]);
    float e[POOL]; float den = 0.f;
    #pragma unroll
    for (int p = 0; p < POOL; p++) { e[p] = expf(sim[p] - m); den += e[p]; }
    float invden = 1.f / den;

    unsigned picked = 0;
    float tw[TOPK]; int ti[TOPK];
    #pragma unroll
    for (int k = 0; k < TOPK; k++) {
        float best = -1.f; int bidx = 0;
        #pragma unroll
        for (int p = 0; p < POOL; p++) {
            bool free_p = ((picked >> p) & 1u) == 0u;
            if (free_p && e[p] > best) { best = e[p]; bidx = p; }
        }
        picked |= (1u << bidx);
        tw[k] = best * invden;
        ti[k] = bidx;
    }

    if (lane == 0) {
        int b = b0 + bi;
        float* topw = ws + 32;
        int*   topi = (int*)(ws + 32) + 5 * B;
        int*   lenp = (int*)(ws + 32) + 10 * B;
        #pragma unroll
        for (int k = 0; k < TOPK; k++) {
            topw[b * TOPK + k] = tw[k];
            topi[b * TOPK + k] = ti[k];
        }
        // match reference fp32 op order: 5 + 59*(1 - q/5)
        float q = qv4[bi];
        float lf = __fadd_rn(5.f, __fmul_rn(59.f, __fsub_rn(1.f, __fdiv_rn(q, 5.f))));
        int len = (int)truncf(lf);
        len = min(max(len, LENGTH_MIN), LENGTH_MAX);
        lenp[b] = len;
    }
}

// out[b,l,:] = (l < len[b]) ? sum_k w_k * pe[idx_k, l, :] : 0
// One block per (b, 8 consecutive l rows). float4 loads (pe stays L2-resident,
// 2.6 MB < 4 MiB/XCD); NON-TEMPORAL float4 stores so the 134 MB output stream
// doesn't evict pe from L2.
__global__ __launch_bounds__(256) void scatter_kernel(
    const float* __restrict__ pe, const float* __restrict__ ws,
    float* __restrict__ out, int B)
{
    int b  = blockIdx.x >> 3;
    int l0 = (blockIdx.x & 7) * 8;
    const float* topw = ws + 32;
    const int*   topi = (const int*)(ws + 32) + 5 * B;
    const int*   lenp = (const int*)(ws + 32) + 10 * B;

    float w[TOPK]; int idx[TOPK];
    #pragma unroll
    for (int k = 0; k < TOPK; k++) {
        w[k]   = topw[b * TOPK + k];
        idx[k] = topi[b * TOPK + k];
    }
    int len = lenp[b];

    int t = threadIdx.x;
    #pragma unroll
    for (int sweep = 0; sweep < 4; sweep++) {
        int l  = l0 + sweep * 2 + (t >> 7);
        int d4 = (t & 127) * 4;
        v4f r = { 0.f, 0.f, 0.f, 0.f };
        if (l < len) {
            #pragma unroll
            for (int k = 0; k < TOPK; k++) {
                v4f pv = *(const v4f*)(pe + (idx[k] * 64 + l) * EMBED_DIM + d4);
                r += pv * w[k];
            }
        }
        __builtin_nontemporal_store(r, (v4f*)(out + ((size_t)(b * 64 + l)) * EMBED_DIM + d4));
    }
}

extern "C" void kernel_launch(void* const* d_in, const int* in_sizes, int n_in,
                              void* d_out, int out_size, void* d_ws, size_t ws_size,
                              hipStream_t stream) {
    // input order: x_embed(unused), quality, keys, prompt_embeddings,
    //              w1, b1, ln_g, ln_b, w2, b2
    const float* quality = (const float*)d_in[1];
    const float* keys    = (const float*)d_in[2];
    const float* pe      = (const float*)d_in[3];
    const float* w1      = (const float*)d_in[4];
    const float* b1      = (const float*)d_in[5];
    const float* ln_g    = (const float*)d_in[6];
    const float* ln_b    = (const float*)d_in[7];
    const float* w2      = (const float*)d_in[8];
    const float* b2      = (const float*)d_in[9];
    float* out = (float*)d_out;
    float* ws  = (float*)d_ws;
    int B = in_sizes[1];

    query_all_kernel<<<B / 4, 256, 0, stream>>>(quality, keys, w1, b1, ln_g, ln_b,
                                                w2, b2, ws, B);
    scatter_kernel<<<B * 8, 256, 0, stream>>>(pe, ws, out, B);
}